// Round 8
// baseline (164.832 us; speedup 1.0000x reference)
//
#include <hip/hip_runtime.h>
#include <math.h>

// Problem constants
#define NB 16
#define NL 128
#define DIN 512
#define NH 256
#define NTAGS 45
#define NM (NB*NL)          // 2048 rows
#define NJ (NL+1)           // 129 arc columns

// ws layout (floats)
#define HID_OFF   0
#define U_OFF     (NM*NH)                 // 524288
#define HV_OFF    (U_OFF + NM*NH)         // 1048576
#define VROOT_OFF (HV_OFF + NM*NH)        // 1572864
#define ACC_OFF   (VROOT_OFF + NH)        // accum(1), done(1), pad

static __device__ __forceinline__ float rdlane(float v, int k) {
    return __int_as_float(__builtin_amdgcn_readlane(__float_as_int(v), k));
}

// ---------------------------------------------------------------------------
// N1: hidden = relu(ctx@W1+b1). 32x32 tiles, BK=32 -> grid (65,8).
// x==64: y<4 -> vroot quarter; y==4 -> zero accum/done.  (benched R6/R7)
// ---------------------------------------------------------------------------
__global__ __launch_bounds__(256) void gemm_hidden(
    const float* __restrict__ A, const float* __restrict__ W,
    const float* __restrict__ bias, const float* __restrict__ root,
    const float* __restrict__ Wp, float* __restrict__ out,
    float* __restrict__ vroot, int* __restrict__ flags)
{
    __shared__ float As[32][34];
    __shared__ float Bs[32][36];
    int tid = threadIdx.x;

    if (blockIdx.x == 64) {
        int y = blockIdx.y;
        if (y < 4) {                       // vroot cols y*64..y*64+63
            __shared__ float part[256];
            int col = y * 64 + (tid & 63);
            int kc = tid >> 6;
            float p = 0.f;
            #pragma unroll 8
            for (int c = kc * 64; c < kc * 64 + 64; c++)
                p += root[c] * Wp[(NH + c) * NH + col];
            part[kc * 64 + (tid & 63)] = p;
            __syncthreads();
            if (tid < 64)
                vroot[y * 64 + tid] = part[tid] + part[64 + tid]
                                    + part[128 + tid] + part[192 + tid];
        } else if (y == 4) {
            if (tid < 2) flags[tid] = 0;   // accum, done
        }
        return;
    }

    int m0 = blockIdx.x * 32;
    int n0 = blockIdx.y * 32;
    int lr = tid >> 3, lq = (tid & 7) * 4;
    int tm = tid >> 4, tn = tid & 15;
    float acc[2][2] = {{0.f}};

    for (int k0 = 0; k0 < DIN; k0 += 32) {
        float4 a4 = *(const float4*)&A[(m0 + lr) * DIN + k0 + lq];
        As[lq + 0][lr] = a4.x; As[lq + 1][lr] = a4.y;
        As[lq + 2][lr] = a4.z; As[lq + 3][lr] = a4.w;
        float4 b4 = *(const float4*)&W[(k0 + lr) * NH + n0 + lq];
        *(float4*)&Bs[lr][lq] = b4;
        __syncthreads();
        #pragma unroll
        for (int kk = 0; kk < 32; kk++) {
            float2 a2 = *(const float2*)&As[kk][tm * 2];
            float2 b2 = *(const float2*)&Bs[kk][tn * 2];
            acc[0][0] += a2.x * b2.x; acc[0][1] += a2.x * b2.y;
            acc[1][0] += a2.y * b2.x; acc[1][1] += a2.y * b2.y;
        }
        __syncthreads();
    }
    int col = n0 + tn * 2;
    float2 bb = *(const float2*)&bias[col];
    #pragma unroll
    for (int r = 0; r < 2; r++) {
        int row = m0 + tm * 2 + r;
        float2 o;
        o.x = fmaxf(acc[r][0] + bb.x, 0.f);
        o.y = fmaxf(acc[r][1] + bb.y, 0.f);
        *(float2*)&out[row * NH + col] = o;
    }
}

// ---------------------------------------------------------------------------
// N2: u = hidden@Wa + bp ; hv = hidden@Wb. 32x32 tiles -> grid (64,16).
// (benched R6/R7)
// ---------------------------------------------------------------------------
__global__ __launch_bounds__(256) void gemm_uv(
    const float* __restrict__ hidden, const float* __restrict__ Wp,
    const float* __restrict__ bp, float* __restrict__ u,
    float* __restrict__ hv)
{
    __shared__ float As[32][34];
    __shared__ float Bs[32][36];
    int tid = threadIdx.x;
    int m0 = blockIdx.x * 32;
    int n0 = blockIdx.y * 32;
    bool isU = (n0 < NH);
    int lr = tid >> 3, lq = (tid & 7) * 4;
    int tm = tid >> 4, tn = tid & 15;
    float acc[2][2] = {{0.f}};

    for (int k0 = 0; k0 < NH; k0 += 32) {
        float4 a4 = *(const float4*)&hidden[(m0 + lr) * NH + k0 + lq];
        As[lq + 0][lr] = a4.x; As[lq + 1][lr] = a4.y;
        As[lq + 2][lr] = a4.z; As[lq + 3][lr] = a4.w;
        int c = k0 + lr;
        float4 b4;
        if (isU) b4 = *(const float4*)&Wp[c * NH + n0 + lq];
        else     b4 = *(const float4*)&Wp[(NH + c) * NH + (n0 - NH) + lq];
        *(float4*)&Bs[lr][lq] = b4;
        __syncthreads();
        #pragma unroll
        for (int kk = 0; kk < 32; kk++) {
            float2 a2 = *(const float2*)&As[kk][tm * 2];
            float2 b2 = *(const float2*)&Bs[kk][tn * 2];
            acc[0][0] += a2.x * b2.x; acc[0][1] += a2.x * b2.y;
            acc[1][0] += a2.y * b2.x; acc[1][1] += a2.y * b2.y;
        }
        __syncthreads();
    }
    if (isU) {
        int col = n0 + tn * 2;
        float2 bb = *(const float2*)&bp[col];
        #pragma unroll
        for (int r = 0; r < 2; r++) {
            int row = m0 + tm * 2 + r;
            float2 o;
            o.x = acc[r][0] + bb.x; o.y = acc[r][1] + bb.y;
            *(float2*)&u[row * NH + col] = o;
        }
    } else {
        int col = (n0 - NH) + tn * 2;
        #pragma unroll
        for (int r = 0; r < 2; r++) {
            int row = m0 + tm * 2 + r;
            float2 o; o.x = acc[r][0]; o.y = acc[r][1];
            *(float2*)&hv[row * NH + col] = o;
        }
    }
}

// ---------------------------------------------------------------------------
// N3: fused scores+loss, LDS-lean version.
// 512 blocks, 4 rows each; wave = row. v staged j-major (stride 68 ->
// rotated banks, optimal b128). Wave-uniform u/wa/v128 broadcast via
// v_readlane from registers (no LDS). Scores in regs; wave softmax;
// label head; last-done block finalizes.
// ---------------------------------------------------------------------------
__global__ __launch_bounds__(256, 2) void fused_score_loss(
    const float* __restrict__ u, const float* __restrict__ hv,
    const float* __restrict__ vroot, const float* __restrict__ W_arc,
    const float* __restrict__ W_lab, const float* __restrict__ b_lab,
    const int* __restrict__ slens, const int* __restrict__ arcs,
    const int* __restrict__ labels, int* __restrict__ flags,
    float* __restrict__ out)
{
    float* accum = (float*)flags;
    int* done = flags + 1;
    __shared__ float vs[128][68];     // j-major, 34.8 KB; banks (4j+k)%32
    __shared__ float sel_s[NH][5];
    __shared__ float ll_s[4][48];
    __shared__ float ce_s[4];
    __shared__ int   arc_sh[4];

    int blk = blockIdx.x;
    int tid = threadIdx.x;
    int r0 = blk * 4;
    int b = r0 >> 7;
    int i_base = r0 & 127;
    int slen = slens[b];
    bool active = (i_base < slen);    // block-uniform

    if (active) {
        int i  = tid >> 6;            // wave id = row in group
        int jl = tid & 63;
        const float* hvb = hv + (size_t)(b * NL) * NH;
        float a0 = 0.f, a1 = 0.f, a2 = 0.f;

        for (int k0 = 0; k0 < NH; k0 += 64) {
            // wave-uniform scalars, one per lane: u-row, W_arc, v-col-128
            float u_reg  = u[(size_t)(r0 + i) * NH + k0 + jl];
            float wa_reg = W_arc[k0 + jl];
            float v1_reg = hvb[(size_t)127 * NH + k0 + jl];
            // stage v cols 0..127 j-major: 2048 float4, 8 per thread
            #pragma unroll
            for (int h = 0; h < 8; h++) {
                int idx = h * 256 + tid;
                int j = idx >> 4, q = idx & 15;
                const float* src = (j == 0) ? (vroot + k0 + q * 4)
                                 : (hvb + (size_t)(j - 1) * NH + k0 + q * 4);
                *(float4*)&vs[j][q * 4] = *(const float4*)src;
            }
            __syncthreads();
            #pragma unroll 4
            for (int kq = 0; kq < 16; kq++) {
                float4 vA = *(const float4*)&vs[jl][kq * 4];
                float4 vB = *(const float4*)&vs[jl + 64][kq * 4];
                float va[4] = {vA.x, vA.y, vA.z, vA.w};
                float vb[4] = {vB.x, vB.y, vB.z, vB.w};
                #pragma unroll
                for (int c = 0; c < 4; c++) {
                    int k = kq * 4 + c;
                    float su  = rdlane(u_reg, k);
                    float swa = rdlane(wa_reg, k);
                    float sv  = rdlane(v1_reg, k);
                    a0 += fmaxf(su + va[c], 0.f) * swa;
                    a1 += fmaxf(su + vb[c], 0.f) * swa;
                    a2 += fmaxf(su + sv,    0.f) * swa;
                }
            }
            __syncthreads();
        }

        // ---- wave-level arc softmax CE (129 cols: a0=jl, a1=jl+64, a2=128)
        int row = r0 + i;
        float m = fmaxf(fmaxf(a0, a1), a2);
        #pragma unroll
        for (int off = 32; off > 0; off >>= 1)
            m = fmaxf(m, __shfl_xor(m, off));
        float e = expf(a0 - m) + expf(a1 - m) + ((jl == 0) ? expf(a2 - m) : 0.f);
        #pragma unroll
        for (int off = 32; off > 0; off >>= 1)
            e += __shfl_xor(e, off);
        int a = arcs[row];                       // wave-uniform
        float s_arc = (a < 64) ? __shfl(a0, a)
                    : (a < 128) ? __shfl(a1, a - 64) : a2;
        if (jl == 0) {
            arc_sh[i] = a;
            ce_s[i] = (m + logf(e)) - s_arc;
        }
        __syncthreads();

        // ---- sel = relu(u_row + v[arc]), staged stride-5 ----
        #pragma unroll
        for (int r = 0; r < 4; r++) {
            int ar = arc_sh[r];
            const float* vr = (ar == 0) ? vroot
                            : (hvb + (size_t)(ar - 1) * NH);
            sel_s[tid][r] = fmaxf(u[(size_t)(r0 + r) * NH + tid] + vr[tid], 0.f);
        }
        __syncthreads();

        // ---- label logits: threads 0..179 -> (row, tag) ----
        if (tid < 180) {
            int r = tid / 45, t = tid - r * 45;
            float lg = b_lab[t];
            #pragma unroll 8
            for (int k = 0; k < NH; k++)
                lg += sel_s[k][r] * W_lab[k * NTAGS + t];
            ll_s[r][t] = lg;
        } else if (tid < 192) {
            int q = tid - 180;
            ll_s[q / 3][45 + q % 3] = -INFINITY;
        }
        __syncthreads();

        // ---- label softmax CE + mask + combine ----
        {
            float y = (jl < 48) ? ll_s[i][jl] : -INFINITY;
            float m2 = y;
            #pragma unroll
            for (int off = 32; off > 0; off >>= 1)
                m2 = fmaxf(m2, __shfl_xor(m2, off));
            float e2 = (jl < 48) ? expf(y - m2) : 0.f;
            #pragma unroll
            for (int off = 32; off > 0; off >>= 1)
                e2 += __shfl_xor(e2, off);
            if (jl == 0) {
                float lab_ce = (m2 + logf(e2)) - ll_s[i][labels[row]];
                bool act = (i_base + i) < slen;
                ce_s[i] = act ? (ce_s[i] + lab_ce) : 0.f;
            }
        }
        __syncthreads();
        if (tid == 0)
            atomicAdd(accum, ce_s[0] + ce_s[1] + ce_s[2] + ce_s[3]);
    }

    // ---- done counter; 512th block finalizes ----
    if (tid == 0) {
        __threadfence();
        int old = atomicAdd(done, 1);
        if (old == 511) {
            float tot = atomicAdd(accum, 0.f);   // coherent read
            int d = 0;
            #pragma unroll
            for (int bb = 0; bb < NB; bb++) d += slens[bb];
            out[0] = 0.5f * tot / fmaxf((float)d, 1.f);
        }
    }
}

extern "C" void kernel_launch(void* const* d_in, const int* in_sizes, int n_in,
                              void* d_out, int out_size, void* d_ws, size_t ws_size,
                              hipStream_t stream) {
    (void)in_sizes; (void)n_in; (void)out_size; (void)ws_size;
    const float* ctx   = (const float*)d_in[0];
    const int*   slens = (const int*)  d_in[1];
    const int*   arcs  = (const int*)  d_in[2];
    const int*   labs  = (const int*)  d_in[3];
    const float* W1    = (const float*)d_in[4];
    const float* b1    = (const float*)d_in[5];
    const float* root  = (const float*)d_in[6];
    const float* Wp    = (const float*)d_in[7];
    const float* bp    = (const float*)d_in[8];
    const float* W_arc = (const float*)d_in[9];
    const float* W_lab = (const float*)d_in[11];
    const float* b_lab = (const float*)d_in[12];
    float* out = (float*)d_out;

    float* ws     = (float*)d_ws;
    float* hidden = ws + HID_OFF;
    float* u      = ws + U_OFF;
    float* hv     = ws + HV_OFF;
    float* vroot  = ws + VROOT_OFF;
    int*   flags  = (int*)(ws + ACC_OFF);

    gemm_hidden<<<dim3(65, 8), 256, 0, stream>>>(ctx, W1, b1, root, Wp,
                                                 hidden, vroot, flags);
    gemm_uv<<<dim3(64, 16), 256, 0, stream>>>(hidden, Wp, bp, u, hv);
    fused_score_loss<<<512, 256, 0, stream>>>(u, hv, vroot, W_arc, W_lab, b_lab,
                                              slens, arcs, labs, flags, out);
}